// Round 1
// baseline (471.982 us; speedup 1.0000x reference)
//
#include <hip/hip_runtime.h>

typedef short short8 __attribute__((ext_vector_type(8)));
typedef float float4v __attribute__((ext_vector_type(4)));
typedef int int4v __attribute__((ext_vector_type(4)));
typedef unsigned short u16;

#define T_LEN 4096
#define DDIM 512
#define BATCH 8
#define MROWS 32768
#define CH 64
#define NC 64   // T_LEN / CH

__device__ __forceinline__ u16 f2b(float x) {
    unsigned u = __float_as_uint(x);
    unsigned r = (u + 0x7FFFu + ((u >> 16) & 1u)) >> 16;
    return (u16)r;
}
__device__ __forceinline__ float sigm(float x) {
    return 1.f / (1.f + __expf(-x));
}

// ---------------- converts ----------------
__global__ __launch_bounds__(256) void cvt_x(const float* __restrict__ x,
                                             u16* __restrict__ xb, size_t n) {
    size_t i = ((size_t)blockIdx.x * 256 + threadIdx.x) * 4;
    if (i < n) {
        float4v v = *(const float4v*)&x[i];
        ushort4 p;
        p.x = f2b(v[0]); p.y = f2b(v[1]); p.z = f2b(v[2]); p.w = f2b(v[3]);
        *(ushort4*)&xb[i] = p;
    }
}

// Wt[j][k] = W[e][k][h], j = e*512+h ; works for all 3 weight tensors
__global__ __launch_bounds__(256) void cvt_wt(const float* __restrict__ W,
                                              u16* __restrict__ Wt, int N) {
    int idx = blockIdx.x * 256 + threadIdx.x;
    if (idx >= N * 512) return;
    int j = idx >> 9;
    int k = idx & 511;
    int e = j >> 9, h = j & 511;
    Wt[(size_t)j * 512 + k] = f2b(W[((size_t)e * 512 + k) * 512 + h]);
}

// ---------------- GEMM + activation epilogue ----------------
// C = A(Mx512 bf16) @ Bt(Nx512 bf16)^T + bias, MODE-specific activation split
// MODE 1: N=1024: e0 -> tanh -> o0(v), e1 -> sigmoid -> o1(f1)
// MODE 2: N=2048: e0 f2->o0, e1 i->o1, e2 o->o2 (sigmoid), e3 z->o3 (tanh)
// MODE 3: N=512 : raw + bias -> o0
template <int MODE>
__global__ __launch_bounds__(256) void gemm_act(
    const u16* __restrict__ A, const u16* __restrict__ Bt,
    const float* __restrict__ bias, float* __restrict__ o0,
    float* __restrict__ o1, float* __restrict__ o2, float* __restrict__ o3) {
    constexpr int K = 512;
    __shared__ u16 lsA[128 * 32];
    __shared__ u16 lsB[128 * 32];
    const int tid = threadIdx.x;
    const int lane = tid & 63;
    const int wid = tid >> 6;
    const int wr = wid >> 1, wc = wid & 1;
    const int l0 = lane & 15, lh = lane >> 4;
    const int bn0 = blockIdx.x * 128;
    const int bm0 = blockIdx.y * 128;

    float4v acc[4][4];
#pragma unroll
    for (int m = 0; m < 4; ++m)
#pragma unroll
        for (int n = 0; n < 4; ++n) acc[m][n] = (float4v){0.f, 0.f, 0.f, 0.f};

    for (int kt = 0; kt < K / 32; ++kt) {
        const int k0 = kt * 32;
#pragma unroll
        for (int i = 0; i < 2; ++i) {
            int flat = tid + i * 256;
            int row = flat >> 2, ks = flat & 3;
            *(int4v*)&lsA[flat * 8] =
                *(const int4v*)&A[(size_t)(bm0 + row) * K + k0 + ks * 8];
            *(int4v*)&lsB[flat * 8] =
                *(const int4v*)&Bt[(size_t)(bn0 + row) * K + k0 + ks * 8];
        }
        __syncthreads();
        short8 af[4], bf[4];
#pragma unroll
        for (int m = 0; m < 4; ++m)
            af[m] = *(const short8*)&lsA[(wr * 64 + m * 16 + l0) * 32 + lh * 8];
#pragma unroll
        for (int n = 0; n < 4; ++n)
            bf[n] = *(const short8*)&lsB[(wc * 64 + n * 16 + l0) * 32 + lh * 8];
#pragma unroll
        for (int m = 0; m < 4; ++m)
#pragma unroll
            for (int n = 0; n < 4; ++n)
                acc[m][n] = __builtin_amdgcn_mfma_f32_16x16x32_bf16(
                    af[m], bf[n], acc[m][n], 0, 0, 0);
        __syncthreads();
    }

#pragma unroll
    for (int m = 0; m < 4; ++m) {
#pragma unroll
        for (int n = 0; n < 4; ++n) {
            int col = bn0 + wc * 64 + n * 16 + l0;
            float bv = bias[col];
#pragma unroll
            for (int r = 0; r < 4; ++r) {
                int row = bm0 + wr * 64 + m * 16 + lh * 4 + r;
                float u = acc[m][n][r] + bv;
                size_t oidx = (size_t)row * 512 + (col & 511);
                if (MODE == 1) {
                    if (col < 512)
                        o0[oidx] = tanhf(u);
                    else
                        o1[oidx] = sigm(u);
                } else if (MODE == 2) {
                    int e = col >> 9;
                    if (e == 0)
                        o0[oidx] = sigm(u);
                    else if (e == 1)
                        o1[oidx] = sigm(u);
                    else if (e == 2)
                        o2[oidx] = sigm(u);
                    else
                        o3[oidx] = tanhf(u);
                } else {
                    o0[oidx] = u;
                }
            }
        }
    }
}

// ---------------- chunked scan ----------------
// recurrence: h_t = f_t * h_{t-1} + g_t,  g = (1-f)*v   (S==1)
//                                         g = (1-f)*v*z (S==2)
template <int S>
__global__ __launch_bounds__(256) void scan_p1(const float* __restrict__ f,
                                               const float* __restrict__ v,
                                               const float* __restrict__ z,
                                               float* __restrict__ cA,
                                               float* __restrict__ cB) {
    int d = ((blockIdx.x & 1) << 8) + threadIdx.x;
    int c = (blockIdx.x >> 1) & (NC - 1);
    int b = blockIdx.x >> 7;
    size_t base = ((size_t)b * T_LEN + c * CH) * DDIM + d;
    float Aa = 1.f, Bb = 0.f;
    for (int t = 0; t < CH; ++t) {
        float ff = f[base];
        float g = (S == 1) ? (1.f - ff) * v[base] : (1.f - ff) * v[base] * z[base];
        Bb = ff * Bb + g;
        Aa *= ff;
        base += DDIM;
    }
    size_t ci = ((size_t)(b * DDIM + d)) * NC + c;
    cA[ci] = Aa;
    cB[ci] = Bb;
}

__global__ __launch_bounds__(256) void scan_p2(float* __restrict__ cA,
                                               const float* __restrict__ cB) {
    int ln = blockIdx.x * 256 + threadIdx.x;  // 0..4095 = b*512+d
    size_t base = (size_t)ln * NC;
    float h = 0.f;
    for (int c = 0; c < NC; ++c) {
        float a = cA[base + c], bb = cB[base + c];
        cA[base + c] = h;  // store carry-in (exclusive)
        h = a * h + bb;
    }
}

// pass3: apply carry, write result as bf16 (h for S==1, h*o for S==2),
// write last-timestep hidden (pre-o) to hid
template <int S>
__global__ __launch_bounds__(256) void scan_p3(
    const float* __restrict__ f, const float* __restrict__ v,
    const float* __restrict__ z, const float* __restrict__ o,
    const float* __restrict__ cA, u16* __restrict__ hb,
    float* __restrict__ hid) {
    int d = ((blockIdx.x & 1) << 8) + threadIdx.x;
    int c = (blockIdx.x >> 1) & (NC - 1);
    int b = blockIdx.x >> 7;
    size_t base = ((size_t)b * T_LEN + c * CH) * DDIM + d;
    float h = cA[((size_t)(b * DDIM + d)) * NC + c];
    for (int t = 0; t < CH; ++t) {
        float ff = f[base];
        float g = (S == 1) ? (1.f - ff) * v[base] : (1.f - ff) * v[base] * z[base];
        h = ff * h + g;
        float w = (S == 1) ? h : h * o[base];
        hb[base] = f2b(w);
        base += DDIM;
    }
    if (c == NC - 1) {
        hid[b * 1024 + (S == 1 ? 0 : 512) + d] = h;
    }
}

// ---------------- launch ----------------
extern "C" void kernel_launch(void* const* d_in, const int* in_sizes, int n_in,
                              void* d_out, int out_size, void* d_ws,
                              size_t ws_size, hipStream_t stream) {
    const float* x = (const float*)d_in[0];
    const float* W_in = (const float*)d_in[1];
    const float* b_in = (const float*)d_in[2];
    const float* W_mid = (const float*)d_in[3];
    const float* b_mid = (const float*)d_in[4];
    const float* W_out = (const float*)d_in[5];
    const float* b_out = (const float*)d_in[6];
    float* out = (float*)d_out;
    char* ws = (char*)d_ws;

    const size_t MB = 1u << 20;
    const size_t MD = (size_t)MROWS * DDIM;  // 16.7M elems

    u16* wt_in = (u16*)(ws);             // 1 MB
    u16* wt_mid = (u16*)(ws + 1 * MB);   // 2 MB
    u16* wt_out = (u16*)(ws + 3 * MB);   // 0.5 MB
    u16* hb = (u16*)(ws + 4 * MB);       // 32 MB (xb -> h1 -> s)
    float* P0 = (float*)(ws + 36 * MB);  // 64 MB
    float* P1 = (float*)(ws + 100 * MB); // 64 MB
    float* P2 = (float*)(ws + 164 * MB); // 64 MB
    float* cA = (float*)(ws + 228 * MB); // 1 MB
    float* cB = (float*)(ws + 229 * MB); // 1 MB
    float* Pz = out;          // z staged in d_out's main region (dead until GEMM3)
    float* hid = out + MD;    // hidden output region

    // convert inputs to bf16
    cvt_x<<<(int)(MD / 4 / 256), 256, 0, stream>>>(x, hb, MD);
    cvt_wt<<<(1024 * 512) / 256, 256, 0, stream>>>(W_in, wt_in, 1024);
    cvt_wt<<<(2048 * 512) / 256, 256, 0, stream>>>(W_mid, wt_mid, 2048);
    cvt_wt<<<(512 * 512) / 256, 256, 0, stream>>>(W_out, wt_out, 512);

    // GEMM1: u = x@W_in -> v(P0)=tanh, f1(P1)=sigmoid
    gemm_act<1><<<dim3(8, 256), 256, 0, stream>>>(hb, wt_in, b_in, P0, P1,
                                                  nullptr, nullptr);
    // scan1: h1 = scan(f1, (1-f1)*v); write h1 as bf16 to hb; hidden_pre
    scan_p1<1><<<1024, 256, 0, stream>>>(P1, P0, nullptr, cA, cB);
    scan_p2<<<16, 256, 0, stream>>>(cA, cB);
    scan_p3<1><<<1024, 256, 0, stream>>>(P1, P0, nullptr, nullptr, cA, hb, hid);

    // GEMM2: u = h1@W_mid -> f2(P0), i(P1), o(P2), z(Pz=d_out)
    gemm_act<2><<<dim3(16, 256), 256, 0, stream>>>(hb, wt_mid, b_mid, P0, P1,
                                                   P2, Pz);
    // scan2: h2 = scan(f2, (1-f2)*i*z); s = h2*o -> bf16 hb; hidden_middle
    scan_p1<2><<<1024, 256, 0, stream>>>(P0, P1, Pz, cA, cB);
    scan_p2<<<16, 256, 0, stream>>>(cA, cB);
    scan_p3<2><<<1024, 256, 0, stream>>>(P0, P1, Pz, P2, cA, hb, hid);

    // GEMM3: out = s@W_out + b_out
    gemm_act<3><<<dim3(4, 256), 256, 0, stream>>>(hb, wt_out, b_out, out,
                                                  nullptr, nullptr, nullptr);
}

// Round 2
// 397.253 us; speedup vs baseline: 1.1881x; 1.1881x over previous
//
#include <hip/hip_runtime.h>

typedef short short8 __attribute__((ext_vector_type(8)));
typedef float float4v __attribute__((ext_vector_type(4)));
typedef unsigned short u16;
typedef unsigned int u32;

#define T_LEN 4096
#define DDIM 512
#define BATCH 8
#define MROWS 32768
#define CH 64
#define NC 64   // T_LEN / CH

__device__ __forceinline__ u16 f2b(float x) {
    unsigned u = __float_as_uint(x);
    unsigned r = (u + 0x7FFFu + ((u >> 16) & 1u)) >> 16;
    return (u16)r;
}
__device__ __forceinline__ float sigm(float x) {
    return 1.f / (1.f + __expf(-x));
}
__device__ __forceinline__ float blo(u32 u) { return __uint_as_float(u << 16); }
__device__ __forceinline__ float bhi(u32 u) { return __uint_as_float(u & 0xFFFF0000u); }
__device__ __forceinline__ u32 pack2(float a, float b) {
    return (u32)f2b(a) | ((u32)f2b(b) << 16);
}

__device__ __forceinline__ void gl2lds16(const u16* g, u16* l) {
    __builtin_amdgcn_global_load_lds(
        (const __attribute__((address_space(1))) void*)g,
        (__attribute__((address_space(3))) void*)l, 16, 0, 0);
}

// ---------------- converts ----------------
__global__ __launch_bounds__(256) void cvt_x(const float* __restrict__ x,
                                             u16* __restrict__ xb, size_t n) {
    size_t i = ((size_t)blockIdx.x * 256 + threadIdx.x) * 4;
    if (i < n) {
        float4v v = *(const float4v*)&x[i];
        ushort4 p;
        p.x = f2b(v[0]); p.y = f2b(v[1]); p.z = f2b(v[2]); p.w = f2b(v[3]);
        *(ushort4*)&xb[i] = p;
    }
}

// Wt[j][k] = W[e][k][h], j = e*512+h
__global__ __launch_bounds__(256) void cvt_wt(const float* __restrict__ W,
                                              u16* __restrict__ Wt, int N) {
    int idx = blockIdx.x * 256 + threadIdx.x;
    if (idx >= N * 512) return;
    int j = idx >> 9;
    int k = idx & 511;
    int e = j >> 9, h = j & 511;
    Wt[(size_t)j * 512 + k] = f2b(W[((size_t)e * 512 + k) * 512 + h]);
}

// ---------------- GEMM + activation epilogue ----------------
// C = A(Mx512 bf16) @ Bt(Nx512 bf16)^T + bias
// MODE 1: N=1024: e0 -> tanh -> o0(v) bf16, e1 -> sigmoid -> o1(f1) bf16
// MODE 2: N=2048: f2->o0, i->o1, o->o2 (sigm), z->o3 (tanh), all bf16
// MODE 3: N=512 : raw + bias -> o0 (f32)
template <int MODE>
__global__ __launch_bounds__(256) void gemm_act(
    const u16* __restrict__ A, const u16* __restrict__ Bt,
    const float* __restrict__ bias, void* __restrict__ o0v,
    void* __restrict__ o1v, void* __restrict__ o2v, void* __restrict__ o3v) {
    constexpr int K = 512;
    __shared__ u16 lsA[128 * 32];
    __shared__ u16 lsB[128 * 32];
    const int tid = threadIdx.x;
    const int lane = tid & 63;
    const int wid = tid >> 6;
    const int wr = wid >> 1, wc = wid & 1;
    const int l0 = lane & 15, lh = lane >> 4;
    const int bn0 = blockIdx.x * 128;
    const int bm0 = blockIdx.y * 128;

    float4v acc[4][4];
#pragma unroll
    for (int m = 0; m < 4; ++m)
#pragma unroll
        for (int n = 0; n < 4; ++n) acc[m][n] = (float4v){0.f, 0.f, 0.f, 0.f};

    const int row = (tid >> 2);          // 0..63 within 256-thread group
    const int ks = tid & 3;

    for (int kt = 0; kt < K / 32; ++kt) {
        const int k0 = kt * 32;
        // async global -> LDS, 16B per lane, lane-linear LDS dest
#pragma unroll
        for (int i = 0; i < 2; ++i) {
            int flat = tid + i * 256;
            int r = flat >> 2, k8 = (flat & 3) * 8;
            gl2lds16(&A[(size_t)(bm0 + r) * K + k0 + k8], &lsA[flat * 8]);
            gl2lds16(&Bt[(size_t)(bn0 + r) * K + k0 + k8], &lsB[flat * 8]);
        }
        __syncthreads();
        short8 af[4], bf[4];
#pragma unroll
        for (int m = 0; m < 4; ++m)
            af[m] = *(const short8*)&lsA[(wr * 64 + m * 16 + l0) * 32 + lh * 8];
#pragma unroll
        for (int n = 0; n < 4; ++n)
            bf[n] = *(const short8*)&lsB[(wc * 64 + n * 16 + l0) * 32 + lh * 8];
#pragma unroll
        for (int m = 0; m < 4; ++m)
#pragma unroll
            for (int n = 0; n < 4; ++n)
                acc[m][n] = __builtin_amdgcn_mfma_f32_16x16x32_bf16(
                    af[m], bf[n], acc[m][n], 0, 0, 0);
        __syncthreads();
    }

#pragma unroll
    for (int m = 0; m < 4; ++m) {
#pragma unroll
        for (int n = 0; n < 4; ++n) {
            int col = bn0 + wc * 64 + n * 16 + l0;
            float bv = bias[col];
#pragma unroll
            for (int r = 0; r < 4; ++r) {
                int rw = bm0 + wr * 64 + m * 16 + lh * 4 + r;
                float u = acc[m][n][r] + bv;
                size_t oidx = (size_t)rw * 512 + (col & 511);
                if (MODE == 1) {
                    if (col < 512)
                        ((u16*)o0v)[oidx] = f2b(tanhf(u));
                    else
                        ((u16*)o1v)[oidx] = f2b(sigm(u));
                } else if (MODE == 2) {
                    int e = col >> 9;
                    if (e == 0)
                        ((u16*)o0v)[oidx] = f2b(sigm(u));
                    else if (e == 1)
                        ((u16*)o1v)[oidx] = f2b(sigm(u));
                    else if (e == 2)
                        ((u16*)o2v)[oidx] = f2b(sigm(u));
                    else
                        ((u16*)o3v)[oidx] = f2b(tanhf(u));
                } else {
                    ((float*)o0v)[oidx] = u;
                }
            }
        }
    }
}

// ---------------- chunked scan (bf16 streams, f32 state) ----------------
// h_t = f_t*h_{t-1} + g_t,  g = (1-f)*v (S==1) | (1-f)*v*z (S==2)
template <int S>
__global__ __launch_bounds__(256) void scan_p1(const u16* __restrict__ f,
                                               const u16* __restrict__ v,
                                               const u16* __restrict__ z,
                                               float* __restrict__ cA,
                                               float* __restrict__ cB) {
    int d0 = threadIdx.x * 2;
    int c = blockIdx.x & (NC - 1);
    int b = blockIdx.x >> 6;
    size_t base = ((size_t)b * T_LEN + c * CH) * DDIM + d0;
    float A0 = 1.f, B0 = 0.f, A1 = 1.f, B1 = 0.f;
    for (int t = 0; t < CH; ++t) {
        u32 fu = *(const u32*)&f[base];
        u32 vu = *(const u32*)&v[base];
        float f0 = blo(fu), f1 = bhi(fu);
        float g0 = (1.f - f0) * blo(vu), g1 = (1.f - f1) * bhi(vu);
        if (S == 2) {
            u32 zu = *(const u32*)&z[base];
            g0 *= blo(zu);
            g1 *= bhi(zu);
        }
        B0 = f0 * B0 + g0; A0 *= f0;
        B1 = f1 * B1 + g1; A1 *= f1;
        base += DDIM;
    }
    size_t ci = ((size_t)(b * DDIM + d0)) * NC + c;
    cA[ci] = A0; cB[ci] = B0;
    cA[ci + NC] = A1; cB[ci + NC] = B1;
}

__global__ __launch_bounds__(256) void scan_p2(float* __restrict__ cA,
                                               const float* __restrict__ cB) {
    int ln = blockIdx.x * 256 + threadIdx.x;  // 0..4095 = b*512+d
    size_t base = (size_t)ln * NC;
    float h = 0.f;
    for (int c = 0; c < NC; ++c) {
        float a = cA[base + c], bb = cB[base + c];
        cA[base + c] = h;  // exclusive carry-in
        h = a * h + bb;
    }
}

template <int S>
__global__ __launch_bounds__(256) void scan_p3(
    const u16* __restrict__ f, const u16* __restrict__ v,
    const u16* __restrict__ z, const u16* __restrict__ o,
    const float* __restrict__ cA, u16* __restrict__ hb,
    float* __restrict__ hid) {
    int d0 = threadIdx.x * 2;
    int c = blockIdx.x & (NC - 1);
    int b = blockIdx.x >> 6;
    size_t base = ((size_t)b * T_LEN + c * CH) * DDIM + d0;
    size_t ci = ((size_t)(b * DDIM + d0)) * NC + c;
    float h0 = cA[ci], h1 = cA[ci + NC];
    for (int t = 0; t < CH; ++t) {
        u32 fu = *(const u32*)&f[base];
        u32 vu = *(const u32*)&v[base];
        float f0 = blo(fu), f1 = bhi(fu);
        float g0 = (1.f - f0) * blo(vu), g1 = (1.f - f1) * bhi(vu);
        if (S == 2) {
            u32 zu = *(const u32*)&z[base];
            g0 *= blo(zu);
            g1 *= bhi(zu);
        }
        h0 = f0 * h0 + g0;
        h1 = f1 * h1 + g1;
        float w0 = h0, w1 = h1;
        if (S == 2) {
            u32 ou = *(const u32*)&o[base];
            w0 *= blo(ou);
            w1 *= bhi(ou);
        }
        *(u32*)&hb[base] = pack2(w0, w1);
        base += DDIM;
    }
    if (c == NC - 1) {
        hid[b * 1024 + (S == 1 ? 0 : 512) + d0] = h0;
        hid[b * 1024 + (S == 1 ? 0 : 512) + d0 + 1] = h1;
    }
}

// ---------------- launch ----------------
extern "C" void kernel_launch(void* const* d_in, const int* in_sizes, int n_in,
                              void* d_out, int out_size, void* d_ws,
                              size_t ws_size, hipStream_t stream) {
    const float* x = (const float*)d_in[0];
    const float* W_in = (const float*)d_in[1];
    const float* b_in = (const float*)d_in[2];
    const float* W_mid = (const float*)d_in[3];
    const float* b_mid = (const float*)d_in[4];
    const float* W_out = (const float*)d_in[5];
    const float* b_out = (const float*)d_in[6];
    float* out = (float*)d_out;
    char* ws = (char*)d_ws;

    const size_t MB = 1u << 20;
    const size_t MD = (size_t)MROWS * DDIM;  // 16.7M elems

    u16* wt_in = (u16*)(ws);              // 1 MB
    u16* wt_mid = (u16*)(ws + 1 * MB);    // 2 MB
    u16* wt_out = (u16*)(ws + 3 * MB);    // 0.5 MB
    u16* hb = (u16*)(ws + 4 * MB);        // 32 MB (xb -> h1 -> s)
    u16* S0 = (u16*)(ws + 36 * MB);       // 32 MB
    u16* S1 = (u16*)(ws + 68 * MB);       // 32 MB
    u16* S2 = (u16*)(ws + 100 * MB);      // 32 MB
    u16* S3 = (u16*)(ws + 132 * MB);      // 32 MB
    float* cA = (float*)(ws + 164 * MB);  // 1 MB
    float* cB = (float*)(ws + 165 * MB);  // 1 MB
    float* hid = out + MD;

    cvt_x<<<(int)(MD / 4 / 256), 256, 0, stream>>>(x, hb, MD);
    cvt_wt<<<(1024 * 512) / 256, 256, 0, stream>>>(W_in, wt_in, 1024);
    cvt_wt<<<(2048 * 512) / 256, 256, 0, stream>>>(W_mid, wt_mid, 2048);
    cvt_wt<<<(512 * 512) / 256, 256, 0, stream>>>(W_out, wt_out, 512);

    // GEMM1: v(S0)=tanh, f1(S1)=sigmoid
    gemm_act<1><<<dim3(8, 256), 256, 0, stream>>>(hb, wt_in, b_in, S0, S1,
                                                  nullptr, nullptr);
    // scan1: h1 = scan(f1, (1-f1)*v) -> hb bf16; hidden_pre
    scan_p1<1><<<512, 256, 0, stream>>>(S1, S0, nullptr, cA, cB);
    scan_p2<<<16, 256, 0, stream>>>(cA, cB);
    scan_p3<1><<<512, 256, 0, stream>>>(S1, S0, nullptr, nullptr, cA, hb, hid);

    // GEMM2: f2(S0), i(S1), o(S2), z(S3)
    gemm_act<2><<<dim3(16, 256), 256, 0, stream>>>(hb, wt_mid, b_mid, S0, S1,
                                                   S2, S3);
    // scan2: h2 = scan(f2, (1-f2)*i*z); s = h2*o -> hb bf16; hidden_middle
    scan_p1<2><<<512, 256, 0, stream>>>(S0, S1, S3, cA, cB);
    scan_p2<<<16, 256, 0, stream>>>(cA, cB);
    scan_p3<2><<<512, 256, 0, stream>>>(S0, S1, S3, S2, cA, hb, hid);

    // GEMM3: out = s@W_out + b_out (f32)
    gemm_act<3><<<dim3(4, 256), 256, 0, stream>>>(hb, wt_out, b_out, out,
                                                  nullptr, nullptr, nullptr);
}

// Round 3
// 359.088 us; speedup vs baseline: 1.3144x; 1.1063x over previous
//
#include <hip/hip_runtime.h>

typedef short short8 __attribute__((ext_vector_type(8)));
typedef float float4v __attribute__((ext_vector_type(4)));
typedef unsigned short u16;
typedef unsigned int u32;

#define T_LEN 4096
#define DDIM 512
#define BATCH 8
#define MROWS 32768
#define CH 64
#define NC 64   // T_LEN / CH

__device__ __forceinline__ u16 f2b(float x) {
    unsigned u = __float_as_uint(x);
    unsigned r = (u + 0x7FFFu + ((u >> 16) & 1u)) >> 16;
    return (u16)r;
}
// fast activations: v_exp_f32 + v_rcp_f32 (≈1ulp, invisible at bf16)
__device__ __forceinline__ float sigm(float x) {
    return __builtin_amdgcn_rcpf(1.f + __builtin_amdgcn_exp2f(-1.44269504f * x));
}
__device__ __forceinline__ float tanh_fast(float x) {
    return 1.f - 2.f * __builtin_amdgcn_rcpf(1.f + __builtin_amdgcn_exp2f(2.88539008f * x));
}
__device__ __forceinline__ float blo(u32 u) { return __uint_as_float(u << 16); }
__device__ __forceinline__ float bhi(u32 u) { return __uint_as_float(u & 0xFFFF0000u); }
__device__ __forceinline__ u32 pack2(float a, float b) {
    return (u32)f2b(a) | ((u32)f2b(b) << 16);
}

__device__ __forceinline__ void gl2lds16(const u16* g, u16* l) {
    __builtin_amdgcn_global_load_lds(
        (const __attribute__((address_space(1))) void*)g,
        (__attribute__((address_space(3))) void*)l, 16, 0, 0);
}

// ---------------- converts ----------------
__global__ __launch_bounds__(256) void cvt_x(const float* __restrict__ x,
                                             u16* __restrict__ xb, size_t n) {
    size_t i = ((size_t)blockIdx.x * 256 + threadIdx.x) * 4;
    if (i < n) {
        float4v v = *(const float4v*)&x[i];
        ushort4 p;
        p.x = f2b(v[0]); p.y = f2b(v[1]); p.z = f2b(v[2]); p.w = f2b(v[3]);
        *(ushort4*)&xb[i] = p;
    }
}

// Wt[j][k] = W[e][k][h], j = e*512+h
__global__ __launch_bounds__(256) void cvt_wt(const float* __restrict__ W,
                                              u16* __restrict__ Wt, int N) {
    int idx = blockIdx.x * 256 + threadIdx.x;
    if (idx >= N * 512) return;
    int j = idx >> 9;
    int k = idx & 511;
    int e = j >> 9, h = j & 511;
    Wt[(size_t)j * 512 + k] = f2b(W[((size_t)e * 512 + k) * 512 + h]);
}

// ---------------- GEMM + activation epilogue, 2-phase dbuf pipeline ----------
// C = A(Mx512 bf16) @ Bt(Nx512 bf16)^T + bias
// MODE 1: N=1024: tanh -> o0(v) bf16 | sigmoid -> o1(f1) bf16
// MODE 2: N=2048: f2->o0, i->o1, o->o2 (sigm), z->o3 (tanh), all bf16
// MODE 3: N=512 : raw + bias -> o0 (f32)
template <int MODE>
__global__ __launch_bounds__(256) void gemm_act(
    const u16* __restrict__ A, const u16* __restrict__ Bt,
    const float* __restrict__ bias, void* __restrict__ o0v,
    void* __restrict__ o1v, void* __restrict__ o2v, void* __restrict__ o3v) {
    constexpr int K = 512;
    constexpr int NKT = K / 32;       // 16
    constexpr int LBUF = 128 * 32;    // u16 elems per buffer
    __shared__ u16 lsA[2][LBUF];
    __shared__ u16 lsB[2][LBUF];
    const int tid = threadIdx.x;
    const int lane = tid & 63;
    const int wid = tid >> 6;
    const int wr = wid >> 1, wc = wid & 1;
    const int l0 = lane & 15, lh = lane >> 4;
    const int bn0 = blockIdx.x * 128;
    const int bm0 = blockIdx.y * 128;

    // staging: thread covers rows (tid>>2) and 64+(tid>>2), 16B at col (tid&3)*8
    const int srow = tid >> 2;
    const int k8 = (tid & 3) * 8;
    const u16* gA0 = &A[(size_t)(bm0 + srow) * K + k8];
    const u16* gA1 = &A[(size_t)(bm0 + 64 + srow) * K + k8];
    const u16* gB0 = &Bt[(size_t)(bn0 + srow) * K + k8];
    const u16* gB1 = &Bt[(size_t)(bn0 + 64 + srow) * K + k8];
    u16* dA0 = &lsA[0][tid * 8];
    u16* dA1 = &lsA[0][(tid + 256) * 8];
    u16* dB0 = &lsB[0][tid * 8];
    u16* dB1 = &lsB[0][(tid + 256) * 8];

    float4v acc[4][4];
#pragma unroll
    for (int m = 0; m < 4; ++m)
#pragma unroll
        for (int n = 0; n < 4; ++n) acc[m][n] = (float4v){0.f, 0.f, 0.f, 0.f};

    // prologue: stage kt=0 into buf 0
    gl2lds16(gA0, dA0);
    gl2lds16(gA1, dA1);
    gl2lds16(gB0, dB0);
    gl2lds16(gB1, dB1);
    __syncthreads();

#pragma unroll
    for (int kt = 0; kt < NKT; ++kt) {
        const int cur = kt & 1, nxt = cur ^ 1;
        // issue next-tile loads FIRST — latency hides under ds_read+MFMA
        if (kt + 1 < NKT) {
            const int off = (kt + 1) * 32;
            gl2lds16(gA0 + off, dA0 + nxt * LBUF);
            gl2lds16(gA1 + off, dA1 + nxt * LBUF);
            gl2lds16(gB0 + off, dB0 + nxt * LBUF);
            gl2lds16(gB1 + off, dB1 + nxt * LBUF);
        }
        short8 af[4], bf[4];
#pragma unroll
        for (int m = 0; m < 4; ++m)
            af[m] = *(const short8*)&lsA[cur][(wr * 64 + m * 16 + l0) * 32 + lh * 8];
#pragma unroll
        for (int n = 0; n < 4; ++n)
            bf[n] = *(const short8*)&lsB[cur][(wc * 64 + n * 16 + l0) * 32 + lh * 8];
        __builtin_amdgcn_s_setprio(1);
#pragma unroll
        for (int m = 0; m < 4; ++m)
#pragma unroll
            for (int n = 0; n < 4; ++n)
                acc[m][n] = __builtin_amdgcn_mfma_f32_16x16x32_bf16(
                    af[m], bf[n], acc[m][n], 0, 0, 0);
        __builtin_amdgcn_s_setprio(0);
        // drains vmcnt (staged loads covered by MFMA above) + barrier; race-free
        __syncthreads();
    }

#pragma unroll
    for (int m = 0; m < 4; ++m) {
#pragma unroll
        for (int n = 0; n < 4; ++n) {
            int col = bn0 + wc * 64 + n * 16 + l0;
            float bv = bias[col];
#pragma unroll
            for (int r = 0; r < 4; ++r) {
                int rw = bm0 + wr * 64 + m * 16 + lh * 4 + r;
                float u = acc[m][n][r] + bv;
                size_t oidx = (size_t)rw * 512 + (col & 511);
                if (MODE == 1) {
                    if (col < 512)
                        ((u16*)o0v)[oidx] = f2b(tanh_fast(u));
                    else
                        ((u16*)o1v)[oidx] = f2b(sigm(u));
                } else if (MODE == 2) {
                    int e = col >> 9;
                    if (e == 0)
                        ((u16*)o0v)[oidx] = f2b(sigm(u));
                    else if (e == 1)
                        ((u16*)o1v)[oidx] = f2b(sigm(u));
                    else if (e == 2)
                        ((u16*)o2v)[oidx] = f2b(sigm(u));
                    else
                        ((u16*)o3v)[oidx] = f2b(tanh_fast(u));
                } else {
                    ((float*)o0v)[oidx] = u;
                }
            }
        }
    }
}

// ---------------- chunked scan (bf16 streams, f32 state) ----------------
// h_t = f_t*h_{t-1} + g_t,  g = (1-f)*v (S==1) | (1-f)*v*z (S==2)
template <int S>
__global__ __launch_bounds__(256) void scan_p1(const u16* __restrict__ f,
                                               const u16* __restrict__ v,
                                               const u16* __restrict__ z,
                                               float* __restrict__ cA,
                                               float* __restrict__ cB) {
    int d0 = threadIdx.x * 2;
    int c = blockIdx.x & (NC - 1);
    int b = blockIdx.x >> 6;
    size_t base = ((size_t)b * T_LEN + c * CH) * DDIM + d0;
    float A0 = 1.f, B0 = 0.f, A1 = 1.f, B1 = 0.f;
    for (int t = 0; t < CH; ++t) {
        u32 fu = *(const u32*)&f[base];
        u32 vu = *(const u32*)&v[base];
        float f0 = blo(fu), f1 = bhi(fu);
        float g0 = (1.f - f0) * blo(vu), g1 = (1.f - f1) * bhi(vu);
        if (S == 2) {
            u32 zu = *(const u32*)&z[base];
            g0 *= blo(zu);
            g1 *= bhi(zu);
        }
        B0 = f0 * B0 + g0; A0 *= f0;
        B1 = f1 * B1 + g1; A1 *= f1;
        base += DDIM;
    }
    size_t ci = ((size_t)(b * DDIM + d0)) * NC + c;
    cA[ci] = A0; cB[ci] = B0;
    cA[ci + NC] = A1; cB[ci + NC] = B1;
}

__global__ __launch_bounds__(256) void scan_p2(float* __restrict__ cA,
                                               const float* __restrict__ cB) {
    int ln = blockIdx.x * 256 + threadIdx.x;  // 0..4095 = b*512+d
    size_t base = (size_t)ln * NC;
    float h = 0.f;
    for (int c = 0; c < NC; ++c) {
        float a = cA[base + c], bb = cB[base + c];
        cA[base + c] = h;  // exclusive carry-in
        h = a * h + bb;
    }
}

template <int S>
__global__ __launch_bounds__(256) void scan_p3(
    const u16* __restrict__ f, const u16* __restrict__ v,
    const u16* __restrict__ z, const u16* __restrict__ o,
    const float* __restrict__ cA, u16* __restrict__ hb,
    float* __restrict__ hid) {
    int d0 = threadIdx.x * 2;
    int c = blockIdx.x & (NC - 1);
    int b = blockIdx.x >> 6;
    size_t base = ((size_t)b * T_LEN + c * CH) * DDIM + d0;
    size_t ci = ((size_t)(b * DDIM + d0)) * NC + c;
    float h0 = cA[ci], h1 = cA[ci + NC];
    for (int t = 0; t < CH; ++t) {
        u32 fu = *(const u32*)&f[base];
        u32 vu = *(const u32*)&v[base];
        float f0 = blo(fu), f1 = bhi(fu);
        float g0 = (1.f - f0) * blo(vu), g1 = (1.f - f1) * bhi(vu);
        if (S == 2) {
            u32 zu = *(const u32*)&z[base];
            g0 *= blo(zu);
            g1 *= bhi(zu);
        }
        h0 = f0 * h0 + g0;
        h1 = f1 * h1 + g1;
        float w0 = h0, w1 = h1;
        if (S == 2) {
            u32 ou = *(const u32*)&o[base];
            w0 *= blo(ou);
            w1 *= bhi(ou);
        }
        *(u32*)&hb[base] = pack2(w0, w1);
        base += DDIM;
    }
    if (c == NC - 1) {
        hid[b * 1024 + (S == 1 ? 0 : 512) + d0] = h0;
        hid[b * 1024 + (S == 1 ? 0 : 512) + d0 + 1] = h1;
    }
}

// ---------------- launch ----------------
extern "C" void kernel_launch(void* const* d_in, const int* in_sizes, int n_in,
                              void* d_out, int out_size, void* d_ws,
                              size_t ws_size, hipStream_t stream) {
    const float* x = (const float*)d_in[0];
    const float* W_in = (const float*)d_in[1];
    const float* b_in = (const float*)d_in[2];
    const float* W_mid = (const float*)d_in[3];
    const float* b_mid = (const float*)d_in[4];
    const float* W_out = (const float*)d_in[5];
    const float* b_out = (const float*)d_in[6];
    float* out = (float*)d_out;
    char* ws = (char*)d_ws;

    const size_t MB = 1u << 20;
    const size_t MD = (size_t)MROWS * DDIM;  // 16.7M elems

    u16* wt_in = (u16*)(ws);              // 1 MB
    u16* wt_mid = (u16*)(ws + 1 * MB);    // 2 MB
    u16* wt_out = (u16*)(ws + 3 * MB);    // 0.5 MB
    u16* hb = (u16*)(ws + 4 * MB);        // 32 MB (xb -> h1 -> s)
    u16* S0 = (u16*)(ws + 36 * MB);       // 32 MB
    u16* S1 = (u16*)(ws + 68 * MB);       // 32 MB
    u16* S2 = (u16*)(ws + 100 * MB);      // 32 MB
    u16* S3 = (u16*)(ws + 132 * MB);      // 32 MB
    float* cA = (float*)(ws + 164 * MB);  // 1 MB
    float* cB = (float*)(ws + 165 * MB);  // 1 MB
    float* hid = out + MD;

    cvt_x<<<(int)(MD / 4 / 256), 256, 0, stream>>>(x, hb, MD);
    cvt_wt<<<(1024 * 512) / 256, 256, 0, stream>>>(W_in, wt_in, 1024);
    cvt_wt<<<(2048 * 512) / 256, 256, 0, stream>>>(W_mid, wt_mid, 2048);
    cvt_wt<<<(512 * 512) / 256, 256, 0, stream>>>(W_out, wt_out, 512);

    // GEMM1: v(S0)=tanh, f1(S1)=sigmoid
    gemm_act<1><<<dim3(8, 256), 256, 0, stream>>>(hb, wt_in, b_in, S0, S1,
                                                  nullptr, nullptr);
    // scan1: h1 = scan(f1, (1-f1)*v) -> hb bf16; hidden_pre
    scan_p1<1><<<512, 256, 0, stream>>>(S1, S0, nullptr, cA, cB);
    scan_p2<<<16, 256, 0, stream>>>(cA, cB);
    scan_p3<1><<<512, 256, 0, stream>>>(S1, S0, nullptr, nullptr, cA, hb, hid);

    // GEMM2: f2(S0), i(S1), o(S2), z(S3)
    gemm_act<2><<<dim3(16, 256), 256, 0, stream>>>(hb, wt_mid, b_mid, S0, S1,
                                                   S2, S3);
    // scan2: h2 = scan(f2, (1-f2)*i*z); s = h2*o -> hb bf16; hidden_middle
    scan_p1<2><<<512, 256, 0, stream>>>(S0, S1, S3, cA, cB);
    scan_p2<<<16, 256, 0, stream>>>(cA, cB);
    scan_p3<2><<<512, 256, 0, stream>>>(S0, S1, S3, S2, cA, hb, hid);

    // GEMM3: out = s@W_out + b_out (f32)
    gemm_act<3><<<dim3(4, 256), 256, 0, stream>>>(hb, wt_out, b_out, out,
                                                  nullptr, nullptr, nullptr);
}